// Round 8
// baseline (328.545 us; speedup 1.0000x reference)
//
#include <hip/hip_runtime.h>

// Problem dims
#define TT 32
#define BB 8
#define DD 512
#define HH 512
#define RR 32
#define OO 512
#define H2 1024

typedef unsigned int uint;
typedef float f32x2 __attribute__((ext_vector_type(2)));

// d_ws float-index offsets
#define OFF_WX    0        // [TT*BB][H2]   262144  (pre-LN then LN'd in place)
#define OFF_HS    262144   // [TT*BB][HH]   131072
#define OFF_COLV  393216   // [2][BB][512] f32x2 = 16384 floats
#define OFF_CNT   409600   // [2][BB] u32 = 16

#define HMW_P 528   // 528 % 32 == 16 -> hmw LDS accesses are exact 2-way (free)

// ---- MALL-coherent (device-visible) coalesced ops — PROVEN round 5/6 path ----
__device__ __forceinline__ uint ld4_mall(const uint* p) {
  uint r;
  asm volatile("global_load_dword %0, %1, off sc0 sc1\n\ts_waitcnt vmcnt(0)"
               : "=v"(r) : "v"(p) : "memory");
  return r;
}
__device__ __forceinline__ f32x2 ld8_mall(const f32x2* p) {
  f32x2 r;
  asm volatile("global_load_dwordx2 %0, %1, off sc0 sc1\n\ts_waitcnt vmcnt(0)"
               : "=v"(r) : "v"(p) : "memory");
  return r;
}
__device__ __forceinline__ void st8_mall(f32x2* p, f32x2 v) {
  asm volatile("global_store_dwordx2 %0, %1, off sc0 sc1" :: "v"(p), "v"(v) : "memory");
}
__device__ __forceinline__ float d4(const float4& a, const float4& b) {
  return a.x*b.x + a.y*b.y + a.z*b.z + a.w*b.w;
}

// ---------------- per-batch per-step body (inlined twice: batches A and B) ----------------
// Block geometry: 8 rows/block, row il = tid>>6 (one wave per row), m = tid&63.
// Element float4 index J = m + 64*q, q in {0,1}.
__device__ __forceinline__ void step_batch(
    int t, int cur, int b, bool last,
    int tid, int ir, int il, int m, int i0, int gi,
    float4 (&dUr)[2], float4 (&tEr)[2], float& vreg, float& wxz, float& wxd,
    const float4 (&wlo)[2], const float4 (&Wdvr)[2],
    const float4 (&upr)[2], const float4 (&lor)[2],
    float rgz, float rbz, float rgd, float rbd,
    float hbl, float hbh, float hmb,
    float mw0, float mw1, float mw2, float mb0, float mb1, float mb2,
    float a_sp, float tau, float c1t,
    float (*nh_s)[HH], float (*te_s)[HH],
    const float* hmw_s, float* mp_s, float (*red_s)[8], f32x2* post_s,
    const float* Wx, float* hsbuf, f32x2* colvF, uint* cnt)
{
  // ---- wait: 64 row-blocks of this batch posted parity `cur` ----
  {
    const uint want = 64u * ((uint)(t >> 1) + 1u);
    if (tid < 64) {
      const uint* cp = cnt + cur*BB + b;
      for (;;) {
        const uint v = ld4_mall(cp);
        if (v >= want) break;
        __builtin_amdgcn_s_sleep(1);
      }
    }
    __syncthreads();
  }
  // ---- one-shot coalesced gather: thread tid reads its (z,dv) pair ----
  const f32x2 rec = ld8_mall(colvF + (size_t)(cur*BB + b)*512 + tid);
  const float whz = rec.x, whd = rec.y;

  // ---- LN stats over 1024 (block-redundant, bitwise identical) ----
  float s1 = whz + whd, s2 = whz*whz + whd*whd;
#pragma unroll
  for (int off = 32; off >= 1; off >>= 1) {
    s1 += __shfl_xor(s1, off);
    s2 += __shfl_xor(s2, off);
  }
  if ((tid & 63) == 0) { red_s[0][tid >> 6] = s1; red_s[1][tid >> 6] = s2; }
  __syncthreads();
  s1 = 0.0f; s2 = 0.0f;
#pragma unroll
  for (int w = 0; w < 8; ++w) { s1 += red_s[0][w]; s2 += red_s[1][w]; }
  const float mu   = s1 * (1.0f / H2);
  const float var  = s2 * (1.0f / H2) - mu * mu;
  const float rstd = rsqrtf(var + 1e-5f);

  // ---- LN + gate + v + nh (thread owns column tid) ----
  const float yz = (whz - mu)*rstd*rgz + rbz + wxz;
  const float yd = (whd - mu)*rstd*rgd + rbd + wxd;
  const float z  = 1.0f / (1.0f + __expf(-yz));
  vreg = vreg + z * (yd - vreg);
  const float nh = fmaxf(vreg, 0.0f);
  nh_s[cur][tid] = nh;
  if (ir == 0) hsbuf[(size_t)(t*BB + b)*HH + tid] = nh;
  if (last) return;                    // final step: nh/hs only
  __syncthreads();                     // nh_s[cur] ready

  // ---- Wh GEMV (8 rows, 1 wave/row) + modulator partials ----
  float glo = 0.0f, gdv = 0.0f;
  float4 h4q[2];
  {
    const float4* nh4 = reinterpret_cast<const float4*>(nh_s[cur]);
#pragma unroll
    for (int q = 0; q < 2; ++q) {
      h4q[q] = nh4[m + 64*q];
      glo += d4(wlo[q],  h4q[q]);
      gdv += d4(Wdvr[q], h4q[q]);
    }
#pragma unroll
    for (int off = 32; off >= 1; off >>= 1) {
      glo += __shfl_xor(glo, off);
      gdv += __shfl_xor(gdv, off);
    }
  }
  {
    const int rr = tid >> 4, kk = tid & 15;
    float part = 0.0f;
#pragma unroll
    for (int j = 0; j < 32; ++j)
      part += hmw_s[rr*HMW_P + kk + 16*j] * nh_s[cur][kk + 16*j];
#pragma unroll
    for (int off = 8; off >= 1; off >>= 1) part += __shfl_xor(part, off);
    if (kk == 0) mp_s[rr] = fmaxf(part + hmb, 0.0f);
  }
  __syncthreads();                     // mp_s ready

  // ---- rsm redundantly in every wave ----
  float r_b, s_b, c2t;
  {
    const float mp = mp_s[tid & 31];
    float a0 = mw0*mp, a1 = mw1*mp, a2 = mw2*mp;
#pragma unroll
    for (int off = 16; off >= 1; off >>= 1) {
      a0 += __shfl_xor(a0, off);
      a1 += __shfl_xor(a1, off);
      a2 += __shfl_xor(a2, off);
    }
    r_b = 1.0f / (1.0f + __expf(-(a0 + mb0)));
    s_b = 1.0f / (1.0f + __expf(-(a1 + mb1)));
    c2t = tau * (a2 + mb2);
  }

  // ---- te own-column update for next step (read [cur], write [1-cur]) ----
  {
    const float teo = te_s[cur][tid];
    te_s[1 - cur][tid] = teo + r_b * (nh_s[1 - cur][tid] - teo);
  }

  // ---- state update + plast; te_new recomputed in-register ----
  const float nh_i  = nh_s[cur][gi];
  const float teo_i = te_s[cur][gi];
  const float hp_i  = nh_s[1 - cur][gi];
  const float te_i  = teo_i + r_b * (hp_i - teo_i);
  float plast = 0.0f;
  {
    const float4* te4o = reinterpret_cast<const float4*>(te_s[cur]);
    const float4* hp4  = reinterpret_cast<const float4*>(nh_s[1 - cur]);
#pragma unroll
    for (int q = 0; q < 2; ++q) {
      const int J = m + 64*q;
      const float4 h4 = h4q[q];
      const float4 to = te4o[J];
      const float4 hp = hp4[J];
#define SGRU_UPD(C) { \
      float ten = to.C + r_b * (hp.C - to.C);             /* (1-r)te + r*h_prev */ \
      float o   = nh_i * ten - h4.C * te_i;               /* outer - outer^T    */ \
      float tEn = tEr[q].C + s_b * (o - tEr[q].C);        /* (1-s)tE + s*o      */ \
      tEr[q].C  = tEn;                                                             \
      float d   = c1t * dUr[q].C + c2t * tEn;             /* (1-tau)dU+tau*m*tE */ \
      d = fminf(d, upr[q].C); d = fmaxf(d, lor[q].C);     /* clip               */ \
      dUr[q].C  = d;                                                               \
      plast = fmaf(d, h4.C, plast); }
      SGRU_UPD(x) SGRU_UPD(y) SGRU_UPD(z) SGRU_UPD(w)
#undef SGRU_UPD
    }
#pragma unroll
    for (int off = 32; off >= 1; off >>= 1) plast += __shfl_xor(plast, off);
  }

  // ---- single-wave coalesced post: 8 records (64B) + drain + one bump ----
  if (m == 0) {
    f32x2 pr;
    pr.x = glo + hbl;
    pr.y = gdv + hbh + a_sp*plast;
    post_s[il] = pr;
  }
  __syncthreads();
  if (tid < 64) {
    if (tid < 8)
      st8_mall(colvF + (size_t)((1 - cur)*BB + b)*512 + i0 + tid, post_s[tid]);
    asm volatile("s_waitcnt vmcnt(0)" ::: "memory");
    if (tid == 0) atomicAdd(cnt + (1 - cur)*BB + b, 1u);
  }

  // ---- Wx prefetch for t+1 (after post, off critical path) ----
  wxz = Wx[(size_t)((t+1)*BB + b)*H2 + tid];
  wxd = Wx[(size_t)((t+1)*BB + b)*H2 + HH + tid];
}

__device__ __forceinline__ void prologue_post(
    int b, int tid, int il, int m, int i0,
    const float4 (&dUr)[2], const float4 (&wlo)[2], const float4 (&Wdvr)[2],
    float hbl, float hbh, float a_sp,
    const float* nh1, f32x2* post_s, f32x2* colvF, uint* cnt)
{
  const float4* h4p = reinterpret_cast<const float4*>(nh1);
  float glo = 0.0f, gdv = 0.0f, plast = 0.0f;
#pragma unroll
  for (int q = 0; q < 2; ++q) {
    const float4 h4 = h4p[m + 64*q];
    glo   += d4(wlo[q],  h4);
    gdv   += d4(Wdvr[q], h4);
    plast += d4(dUr[q],  h4);
  }
#pragma unroll
  for (int off = 32; off >= 1; off >>= 1) {
    glo   += __shfl_xor(glo, off);
    gdv   += __shfl_xor(gdv, off);
    plast += __shfl_xor(plast, off);
  }
  if (m == 0) {
    f32x2 pr;
    pr.x = glo + hbl;
    pr.y = gdv + hbh + a_sp*plast;
    post_s[il] = pr;
  }
  __syncthreads();
  if (tid < 64) {
    if (tid < 8)
      st8_mall(colvF + (size_t)b*512 + i0 + tid, post_s[tid]);
    asm volatile("s_waitcnt vmcnt(0)" ::: "memory");
    if (tid == 0) atomicAdd(cnt + b, 1u);
  }
}

// ---------------- persistent kernel: 256 blocks, 8 rows x 2 batches each ----------------
__global__ __launch_bounds__(512, 1) void sgru_persistent(
    const float* __restrict__ h0,     const float* __restrict__ v0,
    const float* __restrict__ dU0,    const float* __restrict__ tE0,
    const float* __restrict__ te0,
    const float* __restrict__ h2h_w,  const float* __restrict__ h2h_b,
    const float* __restrict__ lnh_g,  const float* __restrict__ lnh_b,
    const float* __restrict__ h2mod_w,const float* __restrict__ h2mod_b,
    const float* __restrict__ mod2h_w,const float* __restrict__ mod2h_b,
    const float* __restrict__ alpha_p,const float* __restrict__ tau_p,
    float* __restrict__ ws)
{
  const int tid = threadIdx.x;
  const int bgi = blockIdx.x & 3;    // batch-group: batches (bgi, bgi+4)
  const int ir  = blockIdx.x >> 2;   // row-block 0..63
  const int b0  = bgi, b1 = bgi + 4;
  const int i0  = ir << 3;           // 8 rows per block
  const int il  = tid >> 6;          // row 0..7 (one wave per row)
  const int m   = tid & 63;
  const int gi  = i0 + il;

  const float* Wx = ws + OFF_WX;
  float* hsbuf    = ws + OFF_HS;
  f32x2* colvF    = (f32x2*)(ws + OFF_COLV);
  uint*  cnt      = (uint*)(ws + OFF_CNT);

  __shared__ float nhA_s[2][HH], teA_s[2][HH];
  __shared__ float nhB_s[2][HH], teB_s[2][HH];
  __shared__ float hmw_s[RR * HMW_P];
  __shared__ float mp_s[RR];
  __shared__ float red_s[2][8];
  __shared__ f32x2 post_s[8];

  const float a_sp  = log1pf(__expf(alpha_p[0]));
  const float inv_a = 1.0f / (a_sp + 1e-8f);
  const float tau   = 1.0f / (1.0f + __expf(-tau_p[0]));
  const float c1t   = 1.0f - tau;

  // ---- shared weights for rows gi (low) and HH+gi (high): 8 floats each ----
  float4 wlo[2], Wdvr[2], upr[2], lor[2];
  {
    const size_t whioff = (size_t)(HH + gi) * HH;
    const size_t wlooff = (size_t)gi * HH;
#pragma unroll
    for (int q = 0; q < 2; ++q) {
      const int J = m + 64*q;
      wlo[q] = *reinterpret_cast<const float4*>(h2h_w + wlooff + 4*J);
      const float4 w = *reinterpret_cast<const float4*>(h2h_w + whioff + 4*J);
      Wdvr[q] = w;
      float4 u, l;
      u.x =  fmaxf(1.0f - w.x, 0.0f) * inv_a;  l.x = -fmaxf(1.0f + w.x, 0.0f) * inv_a;
      u.y =  fmaxf(1.0f - w.y, 0.0f) * inv_a;  l.y = -fmaxf(1.0f + w.y, 0.0f) * inv_a;
      u.z =  fmaxf(1.0f - w.z, 0.0f) * inv_a;  l.z = -fmaxf(1.0f + w.z, 0.0f) * inv_a;
      u.w =  fmaxf(1.0f - w.w, 0.0f) * inv_a;  l.w = -fmaxf(1.0f + w.w, 0.0f) * inv_a;
      upr[q] = u; lor[q] = l;
    }
  }
  // ---- per-batch register state ----
  float4 dUrA[2], tErA[2], dUrB[2], tErB[2];
  {
    const size_t rowA = ((size_t)b0 * HH + gi) * HH;
    const size_t rowB = ((size_t)b1 * HH + gi) * HH;
#pragma unroll
    for (int q = 0; q < 2; ++q) {
      const int J = m + 64*q;
      dUrA[q] = *reinterpret_cast<const float4*>(dU0 + rowA + 4*J);
      tErA[q] = *reinterpret_cast<const float4*>(tE0 + rowA + 4*J);
      dUrB[q] = *reinterpret_cast<const float4*>(dU0 + rowB + 4*J);
      tErB[q] = *reinterpret_cast<const float4*>(tE0 + rowB + 4*J);
    }
  }

  // ---- per-thread constants ----
  const float rgz = lnh_g[tid],      rbz = lnh_b[tid];
  const float rgd = lnh_g[HH + tid], rbd = lnh_b[HH + tid];
  const float hbl = h2h_b[gi], hbh = h2h_b[HH + gi];
  const float hmb = h2mod_b[tid >> 4];
  const float mw0 = mod2h_w[tid & 31];
  const float mw1 = mod2h_w[RR + (tid & 31)];
  const float mw2 = mod2h_w[2*RR + (tid & 31)];
  const float mb0 = mod2h_b[0], mb1 = mod2h_b[1], mb2 = mod2h_b[2];
  float vregA = v0[b0*HH + tid];
  float vregB = v0[b1*HH + tid];

  // ---- LDS staging ----
  nhA_s[1][tid] = h0[b0*HH + tid];
  nhB_s[1][tid] = h0[b1*HH + tid];
  teA_s[0][tid] = te0[b0*HH + tid];
  teB_s[0][tid] = te0[b1*HH + tid];
  for (int idx = tid; idx < RR*HH; idx += 512)
    hmw_s[(idx >> 9)*HMW_P + (idx & 511)] = h2mod_w[idx];
  __syncthreads();

  // ---- prologue posts: Wh(0) for both batches ----
  prologue_post(b0, tid, il, m, i0, dUrA, wlo, Wdvr, hbl, hbh, a_sp,
                nhA_s[1], post_s, colvF, cnt);
  __syncthreads();
  prologue_post(b1, tid, il, m, i0, dUrB, wlo, Wdvr, hbl, hbh, a_sp,
                nhB_s[1], post_s, colvF, cnt);

  float wxzA = Wx[(size_t)(0*BB + b0)*H2 + tid];
  float wxdA = Wx[(size_t)(0*BB + b0)*H2 + HH + tid];
  float wxzB = Wx[(size_t)(0*BB + b1)*H2 + tid];
  float wxdB = Wx[(size_t)(0*BB + b1)*H2 + HH + tid];

#pragma unroll 1
  for (int t = 0; t < TT - 1; ++t) {
    const int cur = t & 1;
    step_batch(t, cur, b0, false, tid, ir, il, m, i0, gi,
               dUrA, tErA, vregA, wxzA, wxdA, wlo, Wdvr, upr, lor,
               rgz, rbz, rgd, rbd, hbl, hbh, hmb,
               mw0, mw1, mw2, mb0, mb1, mb2, a_sp, tau, c1t,
               nhA_s, teA_s, hmw_s, mp_s, red_s, post_s,
               Wx, hsbuf, colvF, cnt);
    step_batch(t, cur, b1, false, tid, ir, il, m, i0, gi,
               dUrB, tErB, vregB, wxzB, wxdB, wlo, Wdvr, upr, lor,
               rgz, rbz, rgd, rbd, hbl, hbh, hmb,
               mw0, mw1, mw2, mb0, mb1, mb2, a_sp, tau, c1t,
               nhB_s, teB_s, hmw_s, mp_s, red_s, post_s,
               Wx, hsbuf, colvF, cnt);
  }
  {  // final step: elementwise + hs only
    const int t = TT - 1, cur = t & 1;
    step_batch(t, cur, b0, true, tid, ir, il, m, i0, gi,
               dUrA, tErA, vregA, wxzA, wxdA, wlo, Wdvr, upr, lor,
               rgz, rbz, rgd, rbd, hbl, hbh, hmb,
               mw0, mw1, mw2, mb0, mb1, mb2, a_sp, tau, c1t,
               nhA_s, teA_s, hmw_s, mp_s, red_s, post_s,
               Wx, hsbuf, colvF, cnt);
    step_batch(t, cur, b1, true, tid, ir, il, m, i0, gi,
               dUrB, tErB, vregB, wxzB, wxdB, wlo, Wdvr, upr, lor,
               rgz, rbz, rgd, rbd, hbl, hbh, hmb,
               mw0, mw1, mw2, mb0, mb1, mb2, a_sp, tau, c1t,
               nhB_s, teB_s, hmw_s, mp_s, red_s, post_s,
               Wx, hsbuf, colvF, cnt);
  }
}

// ---------------- tiled fp32 GEMM: C[M][N] = A[M][K=512] . W[N][K]^T + bias ----------------
#define GBM 32
#define GBN 32
#define GBK 32
__global__ __launch_bounds__(256) void gemm_tn(
    const float* __restrict__ A, const float* __restrict__ W,
    const float* __restrict__ bias, float* __restrict__ C,
    int M, int N)
{
  const int K = 512;
  const int nbn = N / GBN;
  const int m0 = (blockIdx.x / nbn) * GBM;
  const int n0 = (blockIdx.x % nbn) * GBN;
  const int tid = threadIdx.x;
  const int tx = tid & 15;
  const int ty = tid >> 4;
  const int lr = tid >> 3;
  const int lc = tid & 7;
  __shared__ float As[GBK][36];
  __shared__ float Ws[GBK][36];
  float acc[2][2] = {};
  for (int kc = 0; kc < K; kc += GBK) {
    const float4 a0 = *reinterpret_cast<const float4*>(A + (size_t)(m0 + lr)*K + kc + lc*4);
    const float4 w0 = *reinterpret_cast<const float4*>(W + (size_t)(n0 + lr)*K + kc + lc*4);
    __syncthreads();
    As[lc*4+0][lr] = a0.x; As[lc*4+1][lr] = a0.y; As[lc*4+2][lr] = a0.z; As[lc*4+3][lr] = a0.w;
    Ws[lc*4+0][lr] = w0.x; Ws[lc*4+1][lr] = w0.y; Ws[lc*4+2][lr] = w0.z; Ws[lc*4+3][lr] = w0.w;
    __syncthreads();
#pragma unroll
    for (int k = 0; k < GBK; ++k) {
      const float2 am = *reinterpret_cast<const float2*>(&As[k][ty*2]);
      const float2 wn = *reinterpret_cast<const float2*>(&Ws[k][tx*2]);
      acc[0][0] += am.x*wn.x; acc[0][1] += am.x*wn.y;
      acc[1][0] += am.y*wn.x; acc[1][1] += am.y*wn.y;
    }
  }
  const float b0 = bias[n0 + tx*2], b1 = bias[n0 + tx*2 + 1];
  C[(size_t)(m0 + ty*2 + 0)*N + n0 + tx*2]     = acc[0][0] + b0;
  C[(size_t)(m0 + ty*2 + 0)*N + n0 + tx*2 + 1] = acc[0][1] + b1;
  C[(size_t)(m0 + ty*2 + 1)*N + n0 + tx*2]     = acc[1][0] + b0;
  C[(size_t)(m0 + ty*2 + 1)*N + n0 + tx*2 + 1] = acc[1][1] + b1;
}

// ---------------- in-place row LayerNorm (256 rows) + zero counters ----------------
__global__ __launch_bounds__(256) void ln_apply(
    float* __restrict__ Wp, const float* __restrict__ g, const float* __restrict__ b,
    uint* __restrict__ cnt)
{
  const int row = blockIdx.x;
  const int tid = threadIdx.x;
  if (row == 0 && tid < 16) cnt[tid] = 0u;   // [2][8] counters
  float* rp = Wp + (size_t)row * H2;
  float4 v = *reinterpret_cast<const float4*>(rp + tid*4);
  float s1 = v.x + v.y + v.z + v.w;
  float s2 = v.x*v.x + v.y*v.y + v.z*v.z + v.w*v.w;
#pragma unroll
  for (int off = 32; off >= 1; off >>= 1) {
    s1 += __shfl_xor(s1, off);
    s2 += __shfl_xor(s2, off);
  }
  __shared__ float red[2][4];
  if ((tid & 63) == 0) { red[0][tid >> 6] = s1; red[1][tid >> 6] = s2; }
  __syncthreads();
  s1 = red[0][0] + red[0][1] + red[0][2] + red[0][3];
  s2 = red[1][0] + red[1][1] + red[1][2] + red[1][3];
  const float mu   = s1 * (1.0f / H2);
  const float var  = s2 * (1.0f / H2) - mu * mu;
  const float rstd = rsqrtf(var + 1e-5f);
  const float4 gv = *reinterpret_cast<const float4*>(g + tid*4);
  const float4 bv = *reinterpret_cast<const float4*>(b + tid*4);
  v.x = gv.x*(v.x - mu)*rstd + bv.x;
  v.y = gv.y*(v.y - mu)*rstd + bv.y;
  v.z = gv.z*(v.z - mu)*rstd + bv.z;
  v.w = gv.w*(v.w - mu)*rstd + bv.w;
  *reinterpret_cast<float4*>(rp + tid*4) = v;
}

extern "C" void kernel_launch(void* const* d_in, const int* in_sizes, int n_in,
                              void* d_out, int out_size, void* d_ws, size_t ws_size,
                              hipStream_t stream) {
  (void)in_sizes; (void)n_in; (void)out_size; (void)ws_size;
  const float* x        = (const float*)d_in[0];
  const float* h0       = (const float*)d_in[1];
  const float* v0       = (const float*)d_in[2];
  const float* dU0      = (const float*)d_in[3];
  const float* te0      = (const float*)d_in[4];   // trace_e0
  const float* tE0      = (const float*)d_in[5];   // trace_E0
  const float* x2h_w    = (const float*)d_in[6];
  const float* x2h_b    = (const float*)d_in[7];
  const float* h2h_w    = (const float*)d_in[8];
  const float* h2h_b    = (const float*)d_in[9];
  const float* lnx_g    = (const float*)d_in[10];
  const float* lnx_b    = (const float*)d_in[11];
  const float* lnh_g    = (const float*)d_in[12];
  const float* lnh_b    = (const float*)d_in[13];
  const float* h2mod_w  = (const float*)d_in[14];
  const float* h2mod_b  = (const float*)d_in[15];
  const float* mod2h_w  = (const float*)d_in[16];
  const float* mod2h_b  = (const float*)d_in[17];
  const float* alpha    = (const float*)d_in[18];
  const float* tau_U    = (const float*)d_in[19];
  const float* dec_w    = (const float*)d_in[20];
  const float* dec_b    = (const float*)d_in[21];

  float* ws = (float*)d_ws;

  // 1) Wx pre-LN GEMM: [256 x 1024] = x . x2h_w^T  (256 blocks)
  gemm_tn<<<(TT*BB/GBM) * (H2/GBN), 256, 0, stream>>>(x, x2h_w, x2h_b,
                                                      ws + OFF_WX, TT*BB, H2);
  // 2) LN in place (256 rows) + zero sync counters
  ln_apply<<<TT*BB, 256, 0, stream>>>(ws + OFF_WX, lnx_g, lnx_b,
                                      (uint*)(ws + OFF_CNT));

  // 3) persistent recurrent kernel: 256 blocks (1/CU), 512 threads,
  //    8 rows x 2 batches per block (latency hiding across batches)
  sgru_persistent<<<256, 512, 0, stream>>>(h0, v0, dU0, tE0, te0,
                                           h2h_w, h2h_b, lnh_g, lnh_b,
                                           h2mod_w, h2mod_b, mod2h_w, mod2h_b,
                                           alpha, tau_U, ws);

  // 4) decode GEMM: out = hs . dec_w^T + dec_b  (128 blocks)
  gemm_tn<<<(TT*BB/GBM) * (OO/GBN), 256, 0, stream>>>(ws + OFF_HS, dec_w, dec_b,
                                                      (float*)d_out, TT*BB, OO);
}

// Round 9
// 197.240 us; speedup vs baseline: 1.6657x; 1.6657x over previous
//
#include <hip/hip_runtime.h>

// Problem dims
#define TT 32
#define BB 8
#define DD 512
#define HH 512
#define RR 32
#define OO 512
#define H2 1024

typedef unsigned int uint;
typedef float f32x2 __attribute__((ext_vector_type(2)));
typedef uint  u32x4 __attribute__((ext_vector_type(4)));

// d_ws float-index offsets (~1.65 MB used)
#define OFF_WX    0        // [TT*BB][H2]   262144  (pre-LN then LN'd in place)
#define OFF_HS    262144   // [TT*BB][HH]   131072
#define OFF_COLV  393216   // [2][BB][512] f32x2 = 16384 floats
#define OFF_FLG   409600   // [2][BB][32] u32x4 (tag, s1, s2, tag) = 2048 floats

#define HMW_P 528   // 528 % 32 == 16 -> hmw LDS accesses are exact 2-way (free)

// ---- MALL-coherent (device-visible) coalesced ops — proven round-5/6 path ----
__device__ __forceinline__ f32x2 ld8_mall(const f32x2* p) {
  f32x2 r;
  asm volatile("global_load_dwordx2 %0, %1, off sc0 sc1\n\ts_waitcnt vmcnt(0)"
               : "=v"(r) : "v"(p) : "memory");
  return r;
}
__device__ __forceinline__ void st8_mall(f32x2* p, f32x2 v) {
  asm volatile("global_store_dwordx2 %0, %1, off sc0 sc1" :: "v"(p), "v"(v) : "memory");
}
__device__ __forceinline__ u32x4 ld16_mall(const u32x4* p) {
  u32x4 r;
  asm volatile("global_load_dwordx4 %0, %1, off sc0 sc1\n\ts_waitcnt vmcnt(0)"
               : "=v"(r) : "v"(p) : "memory");
  return r;
}
__device__ __forceinline__ void st16_mall(u32x4* p, u32x4 v) {
  asm volatile("global_store_dwordx4 %0, %1, off sc0 sc1" :: "v"(p), "v"(v) : "memory");
}
__device__ __forceinline__ float d4(const float4& a, const float4& b) {
  return a.x*b.x + a.y*b.y + a.z*b.z + a.w*b.w;
}

// ---- wave-0 post: coalesced 128B record store + LN-partials embedded in flag ----
__device__ __forceinline__ void post_flag(f32x2* colv_dst, u32x4* flag_dst,
                                          uint tag, int tid, const f32x2* post_s) {
  if (tid < 64) {
    if (tid < 16) st8_mall(colv_dst + tid, post_s[tid]);   // 16x8B = one 128B txn
    f32x2 pv;
    pv.x = 0.0f; pv.y = 0.0f;
    if (tid < 16) pv = post_s[tid];
    float e1 = pv.x + pv.y, e2 = pv.x*pv.x + pv.y*pv.y;    // stats while store flies
#pragma unroll
    for (int off = 8; off >= 1; off >>= 1) {
      e1 += __shfl_xor(e1, off);
      e2 += __shfl_xor(e2, off);
    }
    asm volatile("s_waitcnt vmcnt(0)" ::: "memory");        // records ack'd (clean queue)
    if (tid == 0) {
      u32x4 fr;
      fr.x = tag; fr.y = __float_as_uint(e1); fr.z = __float_as_uint(e2); fr.w = tag;
      st16_mall(flag_dst, fr);
    }
  }
}

// ---------------- persistent recurrent kernel (round-6 geometry) ----------------
__global__ __launch_bounds__(512, 1) void sgru_persistent(
    const float* __restrict__ h0,     const float* __restrict__ v0,
    const float* __restrict__ dU0,    const float* __restrict__ tE0,
    const float* __restrict__ te0,
    const float* __restrict__ h2h_w,  const float* __restrict__ h2h_b,
    const float* __restrict__ lnh_g,  const float* __restrict__ lnh_b,
    const float* __restrict__ h2mod_w,const float* __restrict__ h2mod_b,
    const float* __restrict__ mod2h_w,const float* __restrict__ mod2h_b,
    const float* __restrict__ alpha_p,const float* __restrict__ tau_p,
    float* __restrict__ ws)
{
  const int tid = threadIdx.x;
  const int b   = blockIdx.x & 7;    // consecutive blockIdx -> XCD round-robin
  const int ir  = blockIdx.x >> 3;   // row-group 0..31
  const int i0  = ir << 4;
  const int il  = tid >> 5;
  const int m   = tid & 31;
  const int gi  = i0 + il;

  const float* Wx = ws + OFF_WX;
  float* hsbuf    = ws + OFF_HS;
  f32x2* colvF    = (f32x2*)(ws + OFF_COLV);   // [parity][b][row] (Wh_z, Wh_dv)
  u32x4* flags16  = (u32x4*)(ws + OFF_FLG);    // [parity][b][block] tag+stats

  __shared__ float nh_s[2][HH];
  __shared__ float te_s[2][HH];
  __shared__ float hmw_s[RR * HMW_P];
  __shared__ float mp_s[RR];
  __shared__ float stat_s[2];
  __shared__ f32x2 post_s[16];

  const float a_sp  = log1pf(__expf(alpha_p[0]));
  const float inv_a = 1.0f / (a_sp + 1e-8f);
  const float tau   = 1.0f / (1.0f + __expf(-tau_p[0]));
  const float c1t   = 1.0f - tau;

  // ---- register-resident state: dU, tE, w_dv row, w_low row, clip bounds ----
  float4 dUr[4], tEr[4], Wdvr[4], wlo[4], upr[4], lor[4];
  {
    const size_t rowoff = ((size_t)b * HH + gi) * HH;
    const size_t whioff = (size_t)(HH + gi) * HH;
    const size_t wlooff = (size_t)gi * HH;
#pragma unroll
    for (int q = 0; q < 4; ++q) {
      const int J = m + 32*q;
      dUr[q] = *reinterpret_cast<const float4*>(dU0 + rowoff + 4*J);
      tEr[q] = *reinterpret_cast<const float4*>(tE0 + rowoff + 4*J);
      wlo[q] = *reinterpret_cast<const float4*>(h2h_w + wlooff + 4*J);
      const float4 w = *reinterpret_cast<const float4*>(h2h_w + whioff + 4*J);
      Wdvr[q] = w;
      float4 u, l;
      u.x =  fmaxf(1.0f - w.x, 0.0f) * inv_a;  l.x = -fmaxf(1.0f + w.x, 0.0f) * inv_a;
      u.y =  fmaxf(1.0f - w.y, 0.0f) * inv_a;  l.y = -fmaxf(1.0f + w.y, 0.0f) * inv_a;
      u.z =  fmaxf(1.0f - w.z, 0.0f) * inv_a;  l.z = -fmaxf(1.0f + w.z, 0.0f) * inv_a;
      u.w =  fmaxf(1.0f - w.w, 0.0f) * inv_a;  l.w = -fmaxf(1.0f + w.w, 0.0f) * inv_a;
      upr[q] = u; lor[q] = l;
    }
  }

  // ---- per-thread constants ----
  const float rgz = lnh_g[tid],      rbz = lnh_b[tid];
  const float rgd = lnh_g[HH + tid], rbd = lnh_b[HH + tid];
  const float hbl = h2h_b[gi], hbh = h2h_b[HH + gi];
  const float hmb = h2mod_b[tid >> 4];
  const float mw0 = mod2h_w[tid & 31];             // redundant per-wave rsm
  const float mw1 = mod2h_w[RR + (tid & 31)];
  const float mw2 = mod2h_w[2*RR + (tid & 31)];
  const float mb0 = mod2h_b[0], mb1 = mod2h_b[1], mb2 = mod2h_b[2];
  float vreg = v0[b*HH + tid];

  // ---- prologue: stage LDS ----
  nh_s[1][tid] = h0[b*HH + tid];     // "prev" for t=0
  te_s[0][tid] = te0[b*HH + tid];    // te entering step 0
  for (int idx = tid; idx < RR*HH; idx += 512)
    hmw_s[(idx >> 9)*HMW_P + (idx & 511)] = h2mod_w[idx];
  __syncthreads();

  // ---- prologue post: Wh(0) from h0/dU0 -> parity 0, tag=1 ----
  {
    const float4* h4p = reinterpret_cast<const float4*>(nh_s[1]);
    float glo = 0.0f, gdv = 0.0f, plast = 0.0f;
#pragma unroll
    for (int q = 0; q < 4; ++q) {
      const float4 h4 = h4p[m + 32*q];
      glo   += d4(wlo[q],  h4);
      gdv   += d4(Wdvr[q], h4);
      plast += d4(dUr[q],  h4);
    }
#pragma unroll
    for (int off = 16; off >= 1; off >>= 1) {
      glo   += __shfl_xor(glo, off);
      gdv   += __shfl_xor(gdv, off);
      plast += __shfl_xor(plast, off);
    }
    if (m == 0) {
      f32x2 pr;
      pr.x = glo + hbl;
      pr.y = gdv + hbh + a_sp*plast;
      post_s[il] = pr;
    }
    __syncthreads();
    post_flag(colvF + (size_t)(0*BB + b)*512 + i0,
              flags16 + (size_t)(0*BB + b)*32 + ir, 1u, tid, post_s);
  }

  float wxz = Wx[(size_t)(0*BB + b)*H2 + tid];
  float wxd = Wx[(size_t)(0*BB + b)*H2 + HH + tid];

  for (int t = 0; t < TT; ++t) {
    const int cur = t & 1;
    const uint want = (uint)(t + 1);

    // ---- wave 0: poll 32 flags (one 512B coalesced txn), reduce embedded stats ----
    if (tid < 64) {
      const u32x4* fp = flags16 + (size_t)(cur*BB + b)*32 + (tid & 31);
      u32x4 f;
      for (;;) {
        f = ld16_mall(fp);
        if (__all((f.x >= want) && (f.w >= want))) break;
        __builtin_amdgcn_s_sleep(1);
      }
      float s1 = __uint_as_float(f.y), s2 = __uint_as_float(f.z);
#pragma unroll
      for (int off = 16; off >= 1; off >>= 1) {   // lanes 0..31 closed under xor
        s1 += __shfl_xor(s1, off);
        s2 += __shfl_xor(s2, off);
      }
      if (tid == 0) {
        const float mu  = s1 * (1.0f / H2);
        const float var = s2 * (1.0f / H2) - mu * mu;
        stat_s[0] = mu;
        stat_s[1] = rsqrtf(var + 1e-5f);
      }
    }
    __syncthreads();                  // stats ready; records globally visible

    // ---- one-shot coalesced gather + LN + gate + v + nh ----
    const f32x2 rec = ld8_mall(colvF + (size_t)(cur*BB + b)*512 + tid);
    const float mu = stat_s[0], rstd = stat_s[1];
    const float yz = (rec.x - mu)*rstd*rgz + rbz + wxz;
    const float yd = (rec.y - mu)*rstd*rgd + rbd + wxd;
    const float z  = 1.0f / (1.0f + __expf(-yz));
    vreg = vreg + z * (yd - vreg);
    const float nh = fmaxf(vreg, 0.0f);
    nh_s[cur][tid] = nh;
    if (ir == 0) hsbuf[(size_t)(t*BB + b)*HH + tid] = nh;
    if (t == TT - 1) return;          // uniform exit; decode kernel follows

    // early Wx prefetch: lands well before the post-drain, keeping it clean
    wxz = Wx[(size_t)((t+1)*BB + b)*H2 + tid];
    wxd = Wx[(size_t)((t+1)*BB + b)*H2 + HH + tid];
    __syncthreads();                  // S1: nh_s[cur] ready

    // ---- Wh GEMV (capture nh frags) + modulator partials ----
    float glo = 0.0f, gdv = 0.0f;
    float4 h4q[4];
    {
      const float4* nh4 = reinterpret_cast<const float4*>(nh_s[cur]);
#pragma unroll
      for (int q = 0; q < 4; ++q) {
        h4q[q] = nh4[m + 32*q];
        glo += d4(wlo[q],  h4q[q]);
        gdv += d4(Wdvr[q], h4q[q]);
      }
#pragma unroll
      for (int off = 16; off >= 1; off >>= 1) {
        glo += __shfl_xor(glo, off);
        gdv += __shfl_xor(gdv, off);
      }
    }
    {
      const int rr = tid >> 4, kk = tid & 15;
      float part = 0.0f;
#pragma unroll
      for (int j = 0; j < 32; ++j)
        part += hmw_s[rr*HMW_P + kk + 16*j] * nh_s[cur][kk + 16*j];
#pragma unroll
      for (int off = 8; off >= 1; off >>= 1) part += __shfl_xor(part, off);
      if (kk == 0) mp_s[rr] = fmaxf(part + hmb, 0.0f);
    }
    __syncthreads();                  // S2: mp_s ready

    // ---- rsm redundantly in every wave ----
    float r_b, s_b, c2t;
    {
      const float mp = mp_s[tid & 31];
      float a0 = mw0*mp, a1 = mw1*mp, a2 = mw2*mp;
#pragma unroll
      for (int off = 16; off >= 1; off >>= 1) {
        a0 += __shfl_xor(a0, off);
        a1 += __shfl_xor(a1, off);
        a2 += __shfl_xor(a2, off);
      }
      r_b = 1.0f / (1.0f + __expf(-(a0 + mb0)));
      s_b = 1.0f / (1.0f + __expf(-(a1 + mb1)));
      c2t = tau * (a2 + mb2);
    }

    // ---- te own-column update for next step (read [cur], write [1-cur]) ----
    {
      const float teo = te_s[cur][tid];
      te_s[1 - cur][tid] = teo + r_b * (nh_s[1 - cur][tid] - teo);
    }

    // ---- state update + plast; te_new recomputed in-register ----
    const float nh_i  = nh_s[cur][gi];
    const float teo_i = te_s[cur][gi];
    const float hp_i  = nh_s[1 - cur][gi];
    const float te_i  = teo_i + r_b * (hp_i - teo_i);
    float plast = 0.0f;
    {
      const float4* te4o = reinterpret_cast<const float4*>(te_s[cur]);
      const float4* hp4  = reinterpret_cast<const float4*>(nh_s[1 - cur]);
#pragma unroll
      for (int q = 0; q < 4; ++q) {
        const int J = m + 32*q;
        const float4 h4 = h4q[q];
        const float4 to = te4o[J];
        const float4 hp = hp4[J];
#define SGRU_UPD(C) { \
        float ten = to.C + r_b * (hp.C - to.C);             /* (1-r)te + r*h_prev */ \
        float o   = nh_i * ten - h4.C * te_i;               /* outer - outer^T    */ \
        float tEn = tEr[q].C + s_b * (o - tEr[q].C);        /* (1-s)tE + s*o      */ \
        tEr[q].C  = tEn;                                                             \
        float d   = c1t * dUr[q].C + c2t * tEn;             /* (1-tau)dU+tau*m*tE */ \
        d = fminf(d, upr[q].C); d = fmaxf(d, lor[q].C);     /* clip               */ \
        dUr[q].C  = d;                                                               \
        plast = fmaf(d, h4.C, plast); }
        SGRU_UPD(x) SGRU_UPD(y) SGRU_UPD(z) SGRU_UPD(w)
#undef SGRU_UPD
      }
#pragma unroll
      for (int off = 16; off >= 1; off >>= 1) plast += __shfl_xor(plast, off);
    }

    // ---- stage 16 records to LDS; wave-0 coalesced post + stats + flag ----
    if (m == 0) {
      f32x2 pr;
      pr.x = glo + hbl;
      pr.y = gdv + hbh + a_sp*plast;
      post_s[il] = pr;
    }
    __syncthreads();
    post_flag(colvF + (size_t)((1 - cur)*BB + b)*512 + i0,
              flags16 + (size_t)((1 - cur)*BB + b)*32 + ir, (uint)(t + 2), tid, post_s);
  }
}

// ---------------- tiled fp32 GEMM: C[M][N] = A[M][K=512] . W[N][K]^T + bias ----------------
#define GBM 32
#define GBN 32
#define GBK 32
__global__ __launch_bounds__(256) void gemm_tn(
    const float* __restrict__ A, const float* __restrict__ W,
    const float* __restrict__ bias, float* __restrict__ C,
    int M, int N)
{
  const int K = 512;
  const int nbn = N / GBN;
  const int m0 = (blockIdx.x / nbn) * GBM;
  const int n0 = (blockIdx.x % nbn) * GBN;
  const int tid = threadIdx.x;
  const int tx = tid & 15;
  const int ty = tid >> 4;
  const int lr = tid >> 3;
  const int lc = tid & 7;
  __shared__ float As[GBK][36];
  __shared__ float Ws[GBK][36];
  float acc[2][2] = {};
  for (int kc = 0; kc < K; kc += GBK) {
    const float4 a0 = *reinterpret_cast<const float4*>(A + (size_t)(m0 + lr)*K + kc + lc*4);
    const float4 w0 = *reinterpret_cast<const float4*>(W + (size_t)(n0 + lr)*K + kc + lc*4);
    __syncthreads();
    As[lc*4+0][lr] = a0.x; As[lc*4+1][lr] = a0.y; As[lc*4+2][lr] = a0.z; As[lc*4+3][lr] = a0.w;
    Ws[lc*4+0][lr] = w0.x; Ws[lc*4+1][lr] = w0.y; Ws[lc*4+2][lr] = w0.z; Ws[lc*4+3][lr] = w0.w;
    __syncthreads();
#pragma unroll
    for (int k = 0; k < GBK; ++k) {
      const float2 am = *reinterpret_cast<const float2*>(&As[k][ty*2]);
      const float2 wn = *reinterpret_cast<const float2*>(&Ws[k][tx*2]);
      acc[0][0] += am.x*wn.x; acc[0][1] += am.x*wn.y;
      acc[1][0] += am.y*wn.x; acc[1][1] += am.y*wn.y;
    }
  }
  const float b0 = bias[n0 + tx*2], b1 = bias[n0 + tx*2 + 1];
  C[(size_t)(m0 + ty*2 + 0)*N + n0 + tx*2]     = acc[0][0] + b0;
  C[(size_t)(m0 + ty*2 + 0)*N + n0 + tx*2 + 1] = acc[0][1] + b1;
  C[(size_t)(m0 + ty*2 + 1)*N + n0 + tx*2]     = acc[1][0] + b0;
  C[(size_t)(m0 + ty*2 + 1)*N + n0 + tx*2 + 1] = acc[1][1] + b1;
}

// ---------------- in-place row LayerNorm (256 rows) + zero flag records ----------------
__global__ __launch_bounds__(256) void ln_apply(
    float* __restrict__ Wp, const float* __restrict__ g, const float* __restrict__ b,
    u32x4* __restrict__ flags16)
{
  const int row = blockIdx.x;
  const int tid = threadIdx.x;
  {  // zero 512 flag records (tag 0 = invalid) across first 2 blocks
    const int idx = row * 256 + tid;
    if (idx < 2*BB*32) {
      u32x4 z; z.x = 0u; z.y = 0u; z.z = 0u; z.w = 0u;
      flags16[idx] = z;
    }
  }
  float* rp = Wp + (size_t)row * H2;
  float4 v = *reinterpret_cast<const float4*>(rp + tid*4);
  float s1 = v.x + v.y + v.z + v.w;
  float s2 = v.x*v.x + v.y*v.y + v.z*v.z + v.w*v.w;
#pragma unroll
  for (int off = 32; off >= 1; off >>= 1) {
    s1 += __shfl_xor(s1, off);
    s2 += __shfl_xor(s2, off);
  }
  __shared__ float red[2][4];
  if ((tid & 63) == 0) { red[0][tid >> 6] = s1; red[1][tid >> 6] = s2; }
  __syncthreads();
  s1 = red[0][0] + red[0][1] + red[0][2] + red[0][3];
  s2 = red[1][0] + red[1][1] + red[1][2] + red[1][3];
  const float mu   = s1 * (1.0f / H2);
  const float var  = s2 * (1.0f / H2) - mu * mu;
  const float rstd = rsqrtf(var + 1e-5f);
  const float4 gv = *reinterpret_cast<const float4*>(g + tid*4);
  const float4 bv = *reinterpret_cast<const float4*>(b + tid*4);
  v.x = gv.x*(v.x - mu)*rstd + bv.x;
  v.y = gv.y*(v.y - mu)*rstd + bv.y;
  v.z = gv.z*(v.z - mu)*rstd + bv.z;
  v.w = gv.w*(v.w - mu)*rstd + bv.w;
  *reinterpret_cast<float4*>(rp + tid*4) = v;
}

extern "C" void kernel_launch(void* const* d_in, const int* in_sizes, int n_in,
                              void* d_out, int out_size, void* d_ws, size_t ws_size,
                              hipStream_t stream) {
  (void)in_sizes; (void)n_in; (void)out_size; (void)ws_size;
  const float* x        = (const float*)d_in[0];
  const float* h0       = (const float*)d_in[1];
  const float* v0       = (const float*)d_in[2];
  const float* dU0      = (const float*)d_in[3];
  const float* te0      = (const float*)d_in[4];   // trace_e0
  const float* tE0      = (const float*)d_in[5];   // trace_E0
  const float* x2h_w    = (const float*)d_in[6];
  const float* x2h_b    = (const float*)d_in[7];
  const float* h2h_w    = (const float*)d_in[8];
  const float* h2h_b    = (const float*)d_in[9];
  const float* lnx_g    = (const float*)d_in[10];
  const float* lnx_b    = (const float*)d_in[11];
  const float* lnh_g    = (const float*)d_in[12];
  const float* lnh_b    = (const float*)d_in[13];
  const float* h2mod_w  = (const float*)d_in[14];
  const float* h2mod_b  = (const float*)d_in[15];
  const float* mod2h_w  = (const float*)d_in[16];
  const float* mod2h_b  = (const float*)d_in[17];
  const float* alpha    = (const float*)d_in[18];
  const float* tau_U    = (const float*)d_in[19];
  const float* dec_w    = (const float*)d_in[20];
  const float* dec_b    = (const float*)d_in[21];

  float* ws = (float*)d_ws;

  // 1) Wx pre-LN GEMM: [256 x 1024] = x . x2h_w^T  (256 blocks)
  gemm_tn<<<(TT*BB/GBM) * (H2/GBN), 256, 0, stream>>>(x, x2h_w, x2h_b,
                                                      ws + OFF_WX, TT*BB, H2);
  // 2) LN in place (256 rows) + zero flag records (tag 0 = invalid)
  ln_apply<<<TT*BB, 256, 0, stream>>>(ws + OFF_WX, lnx_g, lnx_b,
                                      (u32x4*)(ws + OFF_FLG));

  // 3) persistent recurrent kernel: 256 blocks (= #CUs), 512 threads
  sgru_persistent<<<256, 512, 0, stream>>>(h0, v0, dU0, tE0, te0,
                                           h2h_w, h2h_b, lnh_g, lnh_b,
                                           h2mod_w, h2mod_b, mod2h_w, mod2h_b,
                                           alpha, tau_U, ws);

  // 4) decode GEMM: out = hs . dec_w^T + dec_b  (128 blocks)
  gemm_tn<<<(TT*BB/GBM) * (OO/GBN), 256, 0, stream>>>(ws + OFF_HS, dec_w, dec_b,
                                                      (float*)d_out, TT*BB, OO);
}

// Round 11
// 174.685 us; speedup vs baseline: 1.8808x; 1.1291x over previous
//
#include <hip/hip_runtime.h>

// Problem dims
#define TT 32
#define BB 8
#define DD 512
#define HH 512
#define RR 32
#define OO 512
#define H2 1024

typedef unsigned int uint;

// d_ws float-index offsets (~1.64 MB used)
#define OFF_WX    0        // [TT*BB][H2]   262144  (pre-LN then LN'd in place)
#define OFF_HS    262144   // [TT*BB][HH]   131072
#define OFF_COLV  393216   // [2][BB][H2]    16384  (coherent Wh exchange)
#define OFF_FLAGS 409600   // 256 u32 barrier flags

#define AGENT __HIP_MEMORY_SCOPE_AGENT
#define RLX   __ATOMIC_RELAXED

#define HMW_P 528   // 528 % 32 == 16 -> hmw LDS accesses are exact 2-way (free)

__device__ __forceinline__ void st_coh(float* p, float v) {
  __hip_atomic_store(p, v, RLX, AGENT);
}
__device__ __forceinline__ float ld_coh(const float* p) {
  return __hip_atomic_load(const_cast<float*>(p), RLX, AGENT);
}
__device__ __forceinline__ float d4(const float4& a, const float4& b) {
  return a.x*b.x + a.y*b.y + a.z*b.z + a.w*b.w;
}

// ---------------- single-hop all-to-all per-batch barrier (32 blocks) ----------------
// Each block posts flag=seq (compiler's pre-barrier waitcnt drains all waves'
// stores), then wave 0 polls all 32 flags. One coherence round-trip.
__device__ __forceinline__ void bar32(unsigned* flags, int b, int ir,
                                      unsigned seq, int tid) {
  __syncthreads();   // compiler emits s_waitcnt vmcnt(0) before s_barrier
  asm volatile("s_waitcnt vmcnt(0)" ::: "memory");
  if (tid == 0)
    __hip_atomic_store(&flags[b*32 + ir], seq, RLX, AGENT);
  if (tid < 64) {
    for (;;) {
      unsigned v = (tid < 32) ? __hip_atomic_load(&flags[b*32 + tid], RLX, AGENT) : seq;
      if (__all(v >= seq)) break;
      __builtin_amdgcn_s_sleep(1);
    }
  }
  __syncthreads();
}

// ---------------- fused state-update + plast + Wh GEMV -> coherent post ----------------
// Row mapping: il = tid>>5 (row 0..15 of block), m = tid&31, elem j = 4*(m+32q)+c.
template<bool UPDATE>
__device__ __forceinline__ void gemv_step(
    int gi, int m,
    float4 (&dUr)[4], float4 (&tEr)[4],
    const float4 (&Wdvr)[4], const float4 (&wlo)[4],
    const float4 (&upr)[4], const float4 (&lor)[4],
    float s_b, float c1t, float c2t, float a_sp, float hbl, float hbh,
    const float* nh_s, const float* te_s,
    float* post)  // colvG + parity*BB*H2 + b*H2
{
  const float nh_i = nh_s[gi];
  const float te_i = UPDATE ? te_s[gi] : 0.0f;
  const float4* nh4 = reinterpret_cast<const float4*>(nh_s);
  const float4* te4 = reinterpret_cast<const float4*>(te_s);
  float plast = 0.0f, gdv = 0.0f, glo = 0.0f;
#pragma unroll
  for (int q = 0; q < 4; ++q) {
    const int J = m + 32*q;
    const float4 h4 = nh4[J];
    if (UPDATE) {
      const float4 t4 = te4[J];
#define SGRU_UPD(C) { \
      float o   = nh_i * t4.C - h4.C * te_i;                /* outer - outer^T    */ \
      float tEn = tEr[q].C + s_b * (o - tEr[q].C);          /* (1-s)tE + s*o      */ \
      tEr[q].C  = tEn;                                                               \
      float d   = c1t * dUr[q].C + c2t * tEn;               /* (1-tau)dU+tau*m*tE */ \
      d = fminf(d, upr[q].C); d = fmaxf(d, lor[q].C);       /* clip               */ \
      dUr[q].C  = d;                                                                 \
      plast = fmaf(d, h4.C, plast); }
      SGRU_UPD(x) SGRU_UPD(y) SGRU_UPD(z) SGRU_UPD(w)
#undef SGRU_UPD
    } else {
      plast += d4(dUr[q], h4);
    }
    gdv += d4(Wdvr[q], h4);
    glo += d4(wlo[q],  h4);
  }
#pragma unroll
  for (int off = 16; off >= 1; off >>= 1) {
    plast += __shfl_xor(plast, off);
    gdv   += __shfl_xor(gdv, off);
    glo   += __shfl_xor(glo, off);
  }
  if (m == 0) {
    st_coh(&post[gi],      glo + hbl);                    // low col gi
    st_coh(&post[HH + gi], gdv + hbh + a_sp * plast);     // high col HH+gi
  }
}

// ---------------- persistent recurrent kernel: 1 barrier/step ----------------
__global__ __launch_bounds__(512, 1) void sgru_persistent(
    const float* __restrict__ h0,     const float* __restrict__ v0,
    const float* __restrict__ dU0,    const float* __restrict__ tE0,
    const float* __restrict__ te0,
    const float* __restrict__ h2h_w,  const float* __restrict__ h2h_b,
    const float* __restrict__ lnh_g,  const float* __restrict__ lnh_b,
    const float* __restrict__ h2mod_w,const float* __restrict__ h2mod_b,
    const float* __restrict__ mod2h_w,const float* __restrict__ mod2h_b,
    const float* __restrict__ alpha_p,const float* __restrict__ tau_p,
    float* __restrict__ ws)
{
  const int tid = threadIdx.x;
  const int b   = blockIdx.x & 7;    // consecutive blockIdx -> XCD round-robin
  const int ir  = blockIdx.x >> 3;   // row-group 0..31
  const int i0  = ir << 4;
  const int il  = tid >> 5;
  const int m   = tid & 31;
  const int gi  = i0 + il;

  const float* Wx = ws + OFF_WX;
  float* hsbuf    = ws + OFF_HS;
  float* colvG    = ws + OFF_COLV;
  unsigned* flags = (unsigned*)(ws + OFF_FLAGS);

  __shared__ float nh_s[2][HH];        // nh double buffer by parity
  __shared__ float te_s[HH];           // block-local te (redundant)
  __shared__ float hmw_s[RR * HMW_P];  // staged h2mod_w, padded pitch
  __shared__ float mp_s[RR];
  __shared__ float rsm_s[4];
  __shared__ float red_s[2][8];

  const float a_sp  = log1pf(__expf(alpha_p[0]));
  const float inv_a = 1.0f / (a_sp + 1e-8f);
  const float tau   = 1.0f / (1.0f + __expf(-tau_p[0]));
  const float c1t   = 1.0f - tau;

  // ---- register-resident state: dU, tE, w_dv row, w_low row, clip bounds ----
  float4 dUr[4], tEr[4], Wdvr[4], wlo[4], upr[4], lor[4];
  {
    const size_t rowoff = ((size_t)b * HH + gi) * HH;
    const size_t whioff = (size_t)(HH + gi) * HH;
    const size_t wlooff = (size_t)gi * HH;
#pragma unroll
    for (int q = 0; q < 4; ++q) {
      const int J = m + 32*q;
      dUr[q] = *reinterpret_cast<const float4*>(dU0 + rowoff + 4*J);
      tEr[q] = *reinterpret_cast<const float4*>(tE0 + rowoff + 4*J);
      wlo[q] = *reinterpret_cast<const float4*>(h2h_w + wlooff + 4*J);
      const float4 w = *reinterpret_cast<const float4*>(h2h_w + whioff + 4*J);
      Wdvr[q] = w;
      float4 u, l;
      u.x =  fmaxf(1.0f - w.x, 0.0f) * inv_a;  l.x = -fmaxf(1.0f + w.x, 0.0f) * inv_a;
      u.y =  fmaxf(1.0f - w.y, 0.0f) * inv_a;  l.y = -fmaxf(1.0f + w.y, 0.0f) * inv_a;
      u.z =  fmaxf(1.0f - w.z, 0.0f) * inv_a;  l.z = -fmaxf(1.0f + w.z, 0.0f) * inv_a;
      u.w =  fmaxf(1.0f - w.w, 0.0f) * inv_a;  l.w = -fmaxf(1.0f + w.w, 0.0f) * inv_a;
      upr[q] = u; lor[q] = l;
    }
  }

  // ---- per-thread constants in registers ----
  const float rgz = lnh_g[tid],      rbz = lnh_b[tid];
  const float rgd = lnh_g[HH + tid], rbd = lnh_b[HH + tid];
  const float hbl = h2h_b[gi], hbh = h2h_b[HH + gi];
  const float hmb = h2mod_b[tid >> 4];
  const float mw0 = (tid < RR) ? mod2h_w[tid]        : 0.0f;
  const float mw1 = (tid < RR) ? mod2h_w[RR + tid]   : 0.0f;
  const float mw2 = (tid < RR) ? mod2h_w[2*RR + tid] : 0.0f;
  const float mb0 = mod2h_b[0], mb1 = mod2h_b[1], mb2 = mod2h_b[2];
  float vreg = v0[b*HH + tid];

  // ---- prologue: stage LDS, compute Wh(0) from h0, post to buf 0 ----
  nh_s[1][tid] = h0[b*HH + tid];     // "prev" for t=0
  te_s[tid]    = te0[b*HH + tid];
  for (int idx = tid; idx < RR*HH; idx += 512)
    hmw_s[(idx >> 9)*HMW_P + (idx & 511)] = h2mod_w[idx];
  __syncthreads();

  gemv_step<false>(gi, m, dUr, tEr, Wdvr, wlo, upr, lor,
                   0.0f, c1t, 0.0f, a_sp, hbl, hbh,
                   nh_s[1], te_s, colvG + 0*BB*H2 + b*H2);

  float wxz = Wx[(size_t)(0*BB + b)*H2 + tid];
  float wxd = Wx[(size_t)(0*BB + b)*H2 + HH + tid];

  unsigned seq = 0;
  for (int t = 0; t < TT; ++t) {
    const int cur = t & 1;
    bar32(flags, b, ir, ++seq, tid);   // all posts of buf[cur] complete

    // ---- gather the 2 Wh values this thread needs ----
    const float whz = ld_coh(&colvG[cur*BB*H2 + b*H2 + tid]);
    const float whd = ld_coh(&colvG[cur*BB*H2 + b*H2 + HH + tid]);

    // ---- LN stats over 1024 (block-redundant, bitwise identical) ----
    float s1 = whz + whd, s2 = whz*whz + whd*whd;
#pragma unroll
    for (int off = 32; off >= 1; off >>= 1) {
      s1 += __shfl_xor(s1, off);
      s2 += __shfl_xor(s2, off);
    }
    if ((tid & 63) == 0) { red_s[0][tid >> 6] = s1; red_s[1][tid >> 6] = s2; }
    __syncthreads();
    s1 = 0.0f; s2 = 0.0f;
#pragma unroll
    for (int w = 0; w < 8; ++w) { s1 += red_s[0][w]; s2 += red_s[1][w]; }
    const float mu   = s1 * (1.0f / H2);
    const float var  = s2 * (1.0f / H2) - mu * mu;
    const float rstd = rsqrtf(var + 1e-5f);

    // ---- LN + gate + v + nh (thread owns element tid) ----
    const float yz = (whz - mu)*rstd*rgz + rbz + wxz;
    const float yd = (whd - mu)*rstd*rgd + rbd + wxd;
    const float z  = 1.0f / (1.0f + __expf(-yz));
    vreg = vreg + z * (yd - vreg);
    const float nh = fmaxf(vreg, 0.0f);
    nh_s[cur][tid] = nh;
    if (ir == 0) hsbuf[(size_t)(t*BB + b)*HH + tid] = nh;
    if (t == TT - 1) return;           // uniform exit; decode kernel follows

    // prefetch next step's Wx under upcoming latency
    wxz = Wx[(size_t)((t+1)*BB + b)*H2 + tid];
    wxd = Wx[(size_t)((t+1)*BB + b)*H2 + HH + tid];
    __syncthreads();                   // nh_s[cur] ready

    // ---- modulator GEMV from LDS (redundant): r = tid>>4, kk = tid&15 ----
    {
      const int r = tid >> 4, kk = tid & 15;
      float part = 0.0f;
#pragma unroll
      for (int j = 0; j < 32; ++j)
        part += hmw_s[r*HMW_P + kk + 16*j] * nh_s[cur][kk + 16*j];
#pragma unroll
      for (int off = 8; off >= 1; off >>= 1) part += __shfl_xor(part, off);
      if (kk == 0) mp_s[r] = fmaxf(part + hmb, 0.0f);
    }
    __syncthreads();
    if (tid < 64) {                    // wave 0: r/s/m 3x32 dots
      const float mp = (tid < RR) ? mp_s[tid] : 0.0f;
      float a0 = mw0*mp, a1 = mw1*mp, a2 = mw2*mp;
#pragma unroll
      for (int off = 16; off >= 1; off >>= 1) {
        a0 += __shfl_xor(a0, off);
        a1 += __shfl_xor(a1, off);
        a2 += __shfl_xor(a2, off);
      }
      if (tid == 0) {
        rsm_s[0] = 1.0f / (1.0f + __expf(-(a0 + mb0)));
        rsm_s[1] = 1.0f / (1.0f + __expf(-(a1 + mb1)));
        rsm_s[2] = a2 + mb2;
      }
    }
    __syncthreads();
    const float r_b = rsm_s[0];
    const float s_b = rsm_s[1];
    const float c2t = tau * rsm_s[2];

    // ---- te update (redundant): te_n = (1-r)te + r*h_prev ----
    te_s[tid] += r_b * (nh_s[1 - cur][tid] - te_s[tid]);
    __syncthreads();

    // ---- state update + Wh GEMV for next step, post to buf[1-cur] ----
    gemv_step<true>(gi, m, dUr, tEr, Wdvr, wlo, upr, lor,
                    s_b, c1t, c2t, a_sp, hbl, hbh,
                    nh_s[cur], te_s, colvG + (1 - cur)*BB*H2 + b*H2);
  }
}

// ---------------- tiled fp32 GEMM: C[M][N] = A[M][K=512] . W[N][K]^T + bias ----------------
#define GBM 32
#define GBN 32
#define GBK 32
__global__ __launch_bounds__(256) void gemm_tn(
    const float* __restrict__ A, const float* __restrict__ W,
    const float* __restrict__ bias, float* __restrict__ C,
    int M, int N)
{
  const int K = 512;
  const int nbn = N / GBN;
  const int m0 = (blockIdx.x / nbn) * GBM;
  const int n0 = (blockIdx.x % nbn) * GBN;
  const int tid = threadIdx.x;
  const int tx = tid & 15;   // n: tx*2
  const int ty = tid >> 4;   // m: ty*2
  const int lr = tid >> 3;   // 0..31 (load row)
  const int lc = tid & 7;    // 0..7  (k float4)
  __shared__ float As[GBK][36];
  __shared__ float Ws[GBK][36];
  float acc[2][2] = {};
  for (int kc = 0; kc < K; kc += GBK) {
    const float4 a0 = *reinterpret_cast<const float4*>(A + (size_t)(m0 + lr)*K + kc + lc*4);
    const float4 w0 = *reinterpret_cast<const float4*>(W + (size_t)(n0 + lr)*K + kc + lc*4);
    __syncthreads();
    As[lc*4+0][lr] = a0.x; As[lc*4+1][lr] = a0.y; As[lc*4+2][lr] = a0.z; As[lc*4+3][lr] = a0.w;
    Ws[lc*4+0][lr] = w0.x; Ws[lc*4+1][lr] = w0.y; Ws[lc*4+2][lr] = w0.z; Ws[lc*4+3][lr] = w0.w;
    __syncthreads();
#pragma unroll
    for (int k = 0; k < GBK; ++k) {
      const float2 am = *reinterpret_cast<const float2*>(&As[k][ty*2]);
      const float2 wn = *reinterpret_cast<const float2*>(&Ws[k][tx*2]);
      acc[0][0] += am.x*wn.x; acc[0][1] += am.x*wn.y;
      acc[1][0] += am.y*wn.x; acc[1][1] += am.y*wn.y;
    }
  }
  const float b0 = bias[n0 + tx*2], b1 = bias[n0 + tx*2 + 1];
  C[(size_t)(m0 + ty*2 + 0)*N + n0 + tx*2]     = acc[0][0] + b0;
  C[(size_t)(m0 + ty*2 + 0)*N + n0 + tx*2 + 1] = acc[0][1] + b1;
  C[(size_t)(m0 + ty*2 + 1)*N + n0 + tx*2]     = acc[1][0] + b0;
  C[(size_t)(m0 + ty*2 + 1)*N + n0 + tx*2 + 1] = acc[1][1] + b1;
}

// ---------------- in-place row LayerNorm (256 rows) + zero barrier flags ----------------
__global__ __launch_bounds__(256) void ln_apply(
    float* __restrict__ Wp, const float* __restrict__ g, const float* __restrict__ b,
    unsigned* __restrict__ flags)
{
  const int row = blockIdx.x;
  const int tid = threadIdx.x;
  if (row == 0) flags[tid] = 0u;     // 256 barrier flags (seq starts at 1)
  float* rp = Wp + (size_t)row * H2;
  float4 v = *reinterpret_cast<const float4*>(rp + tid*4);
  float s1 = v.x + v.y + v.z + v.w;
  float s2 = v.x*v.x + v.y*v.y + v.z*v.z + v.w*v.w;
#pragma unroll
  for (int off = 32; off >= 1; off >>= 1) {
    s1 += __shfl_xor(s1, off);
    s2 += __shfl_xor(s2, off);
  }
  __shared__ float red[2][4];
  if ((tid & 63) == 0) { red[0][tid >> 6] = s1; red[1][tid >> 6] = s2; }
  __syncthreads();
  s1 = red[0][0] + red[0][1] + red[0][2] + red[0][3];
  s2 = red[1][0] + red[1][1] + red[1][2] + red[1][3];
  const float mu   = s1 * (1.0f / H2);
  const float var  = s2 * (1.0f / H2) - mu * mu;
  const float rstd = rsqrtf(var + 1e-5f);
  const float4 gv = *reinterpret_cast<const float4*>(g + tid*4);
  const float4 bv = *reinterpret_cast<const float4*>(b + tid*4);
  v.x = gv.x*(v.x - mu)*rstd + bv.x;
  v.y = gv.y*(v.y - mu)*rstd + bv.y;
  v.z = gv.z*(v.z - mu)*rstd + bv.z;
  v.w = gv.w*(v.w - mu)*rstd + bv.w;
  *reinterpret_cast<float4*>(rp + tid*4) = v;
}

extern "C" void kernel_launch(void* const* d_in, const int* in_sizes, int n_in,
                              void* d_out, int out_size, void* d_ws, size_t ws_size,
                              hipStream_t stream) {
  (void)in_sizes; (void)n_in; (void)out_size; (void)ws_size;
  const float* x        = (const float*)d_in[0];
  const float* h0       = (const float*)d_in[1];
  const float* v0       = (const float*)d_in[2];
  const float* dU0      = (const float*)d_in[3];
  const float* te0      = (const float*)d_in[4];   // trace_e0
  const float* tE0      = (const float*)d_in[5];   // trace_E0
  const float* x2h_w    = (const float*)d_in[6];
  const float* x2h_b    = (const float*)d_in[7];
  const float* h2h_w    = (const float*)d_in[8];
  const float* h2h_b    = (const float*)d_in[9];
  const float* lnx_g    = (const float*)d_in[10];
  const float* lnx_b    = (const float*)d_in[11];
  const float* lnh_g    = (const float*)d_in[12];
  const float* lnh_b    = (const float*)d_in[13];
  const float* h2mod_w  = (const float*)d_in[14];
  const float* h2mod_b  = (const float*)d_in[15];
  const float* mod2h_w  = (const float*)d_in[16];
  const float* mod2h_b  = (const float*)d_in[17];
  const float* alpha    = (const float*)d_in[18];
  const float* tau_U    = (const float*)d_in[19];
  const float* dec_w    = (const float*)d_in[20];
  const float* dec_b    = (const float*)d_in[21];

  float* ws = (float*)d_ws;

  // 1) Wx pre-LN GEMM: [256 x 1024] = x . x2h_w^T  (256 blocks)
  gemm_tn<<<(TT*BB/GBM) * (H2/GBN), 256, 0, stream>>>(x, x2h_w, x2h_b,
                                                      ws + OFF_WX, TT*BB, H2);
  // 2) LN in place (256 rows) + zero barrier flags
  ln_apply<<<TT*BB, 256, 0, stream>>>(ws + OFF_WX, lnx_g, lnx_b,
                                      (unsigned*)(ws + OFF_FLAGS));

  // 3) persistent recurrent kernel: 256 blocks (= #CUs), 512 threads
  sgru_persistent<<<256, 512, 0, stream>>>(h0, v0, dU0, tE0, te0,
                                           h2h_w, h2h_b, lnh_g, lnh_b,
                                           h2mod_w, h2mod_b, mod2h_w, mod2h_b,
                                           alpha, tau_U, ws);

  // 4) decode GEMM: out = hs . dec_w^T + dec_b  (128 blocks)
  gemm_tn<<<(TT*BB/GBM) * (OO/GBN), 256, 0, stream>>>(ws + OFF_HS, dec_w, dec_b,
                                                      (float*)d_out, TT*BB, OO);
}